// Round 1
// baseline (5505.162 us; speedup 1.0000x reference)
//
#include <hip/hip_runtime.h>
#include <hip/hip_bf16.h>
#include <math.h>

#define T_LEN 4096
#define DIM   2048
#define NH    6
#define DK    256
#define DVh   512
#define KD    1536
#define VD    3072

__device__ __forceinline__ float silu_f(float v){ return v / (1.f + __expf(-v)); }

// ---------------- generic fp32 GEMM: C[M,N] = act(A[M,K] @ B[K,N]) ----------------
// 128x128 tile, BK=16, 256 threads, 8x8 micro-tile. M%128==0, N%128==0, K%16==0.
__global__ __launch_bounds__(256) void gemm_f32(
    const float* __restrict__ A, const float* __restrict__ B, float* __restrict__ C,
    int M, int N, int K, int act)
{
  __shared__ float As[16][128];
  __shared__ float Bs[16][128];
  const int bm = blockIdx.y * 128, bn = blockIdx.x * 128;
  const int tid = threadIdx.x;
  const int tx = tid & 15, ty = tid >> 4;
  float acc[8][8];
#pragma unroll
  for (int i = 0; i < 8; ++i)
#pragma unroll
    for (int j = 0; j < 8; ++j) acc[i][j] = 0.f;

  for (int k0 = 0; k0 < K; k0 += 16) {
#pragma unroll
    for (int i = 0; i < 2; ++i) {
      int li = tid * 2 + i;            // 0..511
      int row = li >> 2;               // 0..127
      int kc  = (li & 3) * 4;          // 0,4,8,12
      float4 a4 = *(const float4*)(A + (size_t)(bm + row) * K + k0 + kc);
      As[kc + 0][row] = a4.x; As[kc + 1][row] = a4.y;
      As[kc + 2][row] = a4.z; As[kc + 3][row] = a4.w;
      int kb = li >> 5;                // 0..15
      int nc = (li & 31) * 4;          // 0..124
      float4 b4 = *(const float4*)(B + (size_t)(k0 + kb) * N + bn + nc);
      *(float4*)&Bs[kb][nc] = b4;
    }
    __syncthreads();
#pragma unroll
    for (int kk = 0; kk < 16; ++kk) {
      float a[8], b[8];
#pragma unroll
      for (int i = 0; i < 8; ++i) a[i] = As[kk][ty * 8 + i];
#pragma unroll
      for (int j = 0; j < 8; ++j) b[j] = Bs[kk][tx * 8 + j];
#pragma unroll
      for (int i = 0; i < 8; ++i)
#pragma unroll
        for (int j = 0; j < 8; ++j) acc[i][j] += a[i] * b[j];
    }
    __syncthreads();
  }
#pragma unroll
  for (int i = 0; i < 8; ++i) {
    size_t row = (size_t)(bm + ty * 8 + i) * N + bn + tx * 8;
#pragma unroll
    for (int j = 0; j < 8; j += 4) {
      float4 o4;
      float v0 = acc[i][j], v1 = acc[i][j+1], v2 = acc[i][j+2], v3 = acc[i][j+3];
      if (act == 1) { v0 = silu_f(v0); v1 = silu_f(v1); v2 = silu_f(v2); v3 = silu_f(v3); }
      o4.x = v0; o4.y = v1; o4.z = v2; o4.w = v3;
      *(float4*)(C + row + j) = o4;
    }
  }
}

// ---------------- dyn = tg @ gen_w2 : [T,256]@[256,4] ----------------
__global__ __launch_bounds__(256) void proj_dyn(
    const float* __restrict__ tg, const float* __restrict__ w2, float* __restrict__ dyn)
{
  int t = blockIdx.x, tid = threadIdx.x;
  float g = tg[(size_t)t * 256 + tid];
  float p[4];
#pragma unroll
  for (int j = 0; j < 4; ++j) p[j] = g * w2[tid * 4 + j];
#pragma unroll
  for (int j = 0; j < 4; ++j)
    for (int m = 32; m >= 1; m >>= 1) p[j] += __shfl_xor(p[j], m);
  __shared__ float red[4][4];
  if ((tid & 63) == 0) {
    int w = tid >> 6;
#pragma unroll
    for (int j = 0; j < 4; ++j) red[w][j] = p[j];
  }
  __syncthreads();
  if (tid < 4) dyn[(size_t)t * 4 + tid] = red[0][tid] + red[1][tid] + red[2][tid] + red[3][tid];
}

// ---------------- beta = sigmoid(h@Wb), eg = exp(-exp(A_log)*softplus(h@Wa + dt_bias)) ----------------
__global__ __launch_bounds__(256) void proj_bg(
    const float* __restrict__ h, const float* __restrict__ Wb, const float* __restrict__ Wa,
    const float* __restrict__ A_log, const float* __restrict__ dt_bias,
    float* __restrict__ beta, float* __restrict__ eg)
{
  int t = blockIdx.x, tid = threadIdx.x;
  float pb[6], pa[6];
#pragma unroll
  for (int j = 0; j < 6; ++j) { pb[j] = 0.f; pa[j] = 0.f; }
  for (int d = tid; d < DIM; d += 256) {
    float hv = h[(size_t)t * DIM + d];
#pragma unroll
    for (int j = 0; j < 6; ++j) {
      pb[j] += hv * Wb[d * 6 + j];
      pa[j] += hv * Wa[d * 6 + j];
    }
  }
#pragma unroll
  for (int j = 0; j < 6; ++j)
    for (int m = 32; m >= 1; m >>= 1) { pb[j] += __shfl_xor(pb[j], m); pa[j] += __shfl_xor(pa[j], m); }
  __shared__ float rb[4][6], ra[4][6];
  if ((tid & 63) == 0) {
    int w = tid >> 6;
#pragma unroll
    for (int j = 0; j < 6; ++j) { rb[w][j] = pb[j]; ra[w][j] = pa[j]; }
  }
  __syncthreads();
  if (tid < 6) {
    int j = tid;
    float sb = rb[0][j] + rb[1][j] + rb[2][j] + rb[3][j];
    float sa = ra[0][j] + ra[1][j] + ra[2][j] + ra[3][j];
    beta[(size_t)t * 6 + j] = 1.f / (1.f + expf(-sb));
    float z = sa + dt_bias[j];
    float sp = (z > 20.f) ? z : log1pf(expf(z));
    eg[(size_t)t * 6 + j] = expf(-expf(A_log[j]) * sp);
  }
}

// ---------------- causal dynamic conv + silu ----------------
__global__ __launch_bounds__(256) void conv_kernel(
    const float* __restrict__ x, const float* __restrict__ dyn,
    const float* __restrict__ cw, float* __restrict__ v)
{
  int c = blockIdx.x * 256 + threadIdx.x;
  int t = blockIdx.y;
  float4 w4 = ((const float4*)cw)[c];
  float d0 = dyn[t * 4 + 0], d1 = dyn[t * 4 + 1], d2 = dyn[t * 4 + 2], d3 = dyn[t * 4 + 3];
  float acc = (w4.w + d3) * x[(size_t)t * VD + c];
  if (t >= 1) acc += (w4.z + d2) * x[(size_t)(t - 1) * VD + c];
  if (t >= 2) acc += (w4.y + d1) * x[(size_t)(t - 2) * VD + c];
  if (t >= 3) acc += (w4.x + d0) * x[(size_t)(t - 3) * VD + c];
  v[(size_t)t * VD + c] = silu_f(acc);
}

// ---------------- in-place l2norm over last 256, times scale ----------------
__global__ __launch_bounds__(64) void l2norm_k(float* __restrict__ x, float scale)
{
  size_t base = (size_t)blockIdx.x * 256;
  int tid = threadIdx.x;
  float4 v = ((float4*)(x + base))[tid];
  float ss = v.x * v.x + v.y * v.y + v.z * v.z + v.w * v.w;
  for (int m = 32; m >= 1; m >>= 1) ss += __shfl_xor(ss, m);
  float r = rsqrtf(ss + 1e-6f) * scale;
  v.x *= r; v.y *= r; v.z *= r; v.w *= r;
  ((float4*)(x + base))[tid] = v;
}

// ---------------- sequential gated delta-rule scan ----------------
// grid (32, 6): blockIdx.x = 16-col group of DV, blockIdx.y = head.
// 256 threads: col = tid>>4 (16 cols), sub = tid&15 (16 lanes per col, contiguous).
// Each thread holds S[sub + 16*i][c] for i=0..15 in registers.
__global__ __launch_bounds__(256) void scan_kernel(
    const float* __restrict__ Q, const float* __restrict__ K,
    const float* __restrict__ V, const float* __restrict__ EG,
    const float* __restrict__ BETA, float* __restrict__ O)
{
  const int h = blockIdx.y;
  const int c = blockIdx.x * 16 + (threadIdx.x >> 4);
  const int sub = threadIdx.x & 15;

  float s[16];
#pragma unroll
  for (int i = 0; i < 16; ++i) s[i] = 0.f;

  const float* kp = K + h * DK + sub;
  const float* qp = Q + h * DK + sub;
  const float* vp = V + h * DVh + c;

  float kr[2][16], qr[2][16], vt[2], ee[2], bb[2];

  // preload t = 0 into phase 0
  {
#pragma unroll
    for (int i = 0; i < 16; ++i) { kr[0][i] = kp[16 * i]; qr[0][i] = qp[16 * i]; }
    vt[0] = vp[0]; ee[0] = EG[h]; bb[0] = BETA[h];
  }

  for (int t = 0; t < T_LEN; t += 2) {
    // prefetch t+1 -> phase 1 (t+1 < T_LEN always: T even)
    {
      size_t off = (size_t)(t + 1) * KD;
#pragma unroll
      for (int i = 0; i < 16; ++i) { kr[1][i] = kp[off + 16 * i]; qr[1][i] = qp[off + 16 * i]; }
      vt[1] = vp[(size_t)(t + 1) * VD];
      ee[1] = EG[(t + 1) * 6 + h]; bb[1] = BETA[(t + 1) * 6 + h];
    }
    // step t (phase 0)
    {
      float p = 0.f;
#pragma unroll
      for (int i = 0; i < 16; ++i) p += kr[0][i] * s[i];
      p += __shfl_xor(p, 1); p += __shfl_xor(p, 2); p += __shfl_xor(p, 4); p += __shfl_xor(p, 8);
      float dv = (vt[0] - ee[0] * p) * bb[0];
      float oa = 0.f;
#pragma unroll
      for (int i = 0; i < 16; ++i) { s[i] = ee[0] * s[i] + kr[0][i] * dv; oa += qr[0][i] * s[i]; }
      oa += __shfl_xor(oa, 1); oa += __shfl_xor(oa, 2); oa += __shfl_xor(oa, 4); oa += __shfl_xor(oa, 8);
      if (sub == 0) O[(size_t)t * VD + h * DVh + c] = oa;
    }
    // prefetch t+2 -> phase 0
    {
      int t2 = (t + 2 < T_LEN) ? (t + 2) : (T_LEN - 1);
      size_t off = (size_t)t2 * KD;
#pragma unroll
      for (int i = 0; i < 16; ++i) { kr[0][i] = kp[off + 16 * i]; qr[0][i] = qp[off + 16 * i]; }
      vt[0] = vp[(size_t)t2 * VD];
      ee[0] = EG[t2 * 6 + h]; bb[0] = BETA[t2 * 6 + h];
    }
    // step t+1 (phase 1)
    {
      float p = 0.f;
#pragma unroll
      for (int i = 0; i < 16; ++i) p += kr[1][i] * s[i];
      p += __shfl_xor(p, 1); p += __shfl_xor(p, 2); p += __shfl_xor(p, 4); p += __shfl_xor(p, 8);
      float dv = (vt[1] - ee[1] * p) * bb[1];
      float oa = 0.f;
#pragma unroll
      for (int i = 0; i < 16; ++i) { s[i] = ee[1] * s[i] + kr[1][i] * dv; oa += qr[1][i] * s[i]; }
      oa += __shfl_xor(oa, 1); oa += __shfl_xor(oa, 2); oa += __shfl_xor(oa, 4); oa += __shfl_xor(oa, 8);
      if (sub == 0) O[(size_t)(t + 1) * VD + h * DVh + c] = oa;
    }
  }
}

// ---------------- gated RMSNorm: out = o*rsqrt(mean(o^2)+eps)*nw*silu(gate) ----------------
__global__ __launch_bounds__(256) void norm_gate(
    const float* __restrict__ o, const float* __restrict__ gate,
    const float* __restrict__ nw, float* __restrict__ out)
{
  int th = blockIdx.x, tid = threadIdx.x;
  size_t base = (size_t)th * DVh;
  float x0 = o[base + tid], x1 = o[base + 256 + tid];
  float ss = x0 * x0 + x1 * x1;
  for (int m = 32; m >= 1; m >>= 1) ss += __shfl_xor(ss, m);
  __shared__ float red[4];
  if ((tid & 63) == 0) red[tid >> 6] = ss;
  __syncthreads();
  float rms = rsqrtf((red[0] + red[1] + red[2] + red[3]) * (1.f / 512.f) + 1e-5f);
  float g0 = gate[base + tid], g1 = gate[base + 256 + tid];
  out[base + tid]       = x0 * rms * nw[tid]       * silu_f(g0);
  out[base + 256 + tid] = x1 * rms * nw[tid + 256] * silu_f(g1);
}

extern "C" void kernel_launch(void* const* d_in, const int* in_sizes, int n_in,
                              void* d_out, int out_size, void* d_ws, size_t ws_size,
                              hipStream_t stream)
{
  const float* h       = (const float*)d_in[0];
  const float* Wq      = (const float*)d_in[1];
  const float* Wk      = (const float*)d_in[2];
  const float* Wv      = (const float*)d_in[3];
  const float* Wb      = (const float*)d_in[4];
  const float* Wa      = (const float*)d_in[5];
  const float* Wg      = (const float*)d_in[6];
  const float* Wo      = (const float*)d_in[7];
  const float* A_log   = (const float*)d_in[8];
  const float* dt_bias = (const float*)d_in[9];
  const float* conv_w  = (const float*)d_in[10];
  const float* gen_w1  = (const float*)d_in[11];
  const float* gen_w2  = (const float*)d_in[12];
  const float* norm_w  = (const float*)d_in[13];
  float* out = (float*)d_out;

  float* ws   = (float*)d_ws;
  float* q    = ws;                         // T*KD   = 6291456
  float* k    = q    + (size_t)T_LEN * KD;  // 6291456
  float* x    = k    + (size_t)T_LEN * KD;  // T*VD   = 12582912
  float* v    = x    + (size_t)T_LEN * VD;
  float* gate = v    + (size_t)T_LEN * VD;
  float* tg   = gate + (size_t)T_LEN * VD;  // T*256
  float* dyn  = tg   + (size_t)T_LEN * 256; // T*4
  float* beta = dyn  + (size_t)T_LEN * 4;   // T*6
  float* eg   = beta + (size_t)T_LEN * 6;   // T*6

  dim3 blk(256);
  // projections off h
  gemm_f32<<<dim3(KD / 128, T_LEN / 128), blk, 0, stream>>>(h, Wq, q,    T_LEN, KD,  DIM, 1);
  gemm_f32<<<dim3(KD / 128, T_LEN / 128), blk, 0, stream>>>(h, Wk, k,    T_LEN, KD,  DIM, 1);
  gemm_f32<<<dim3(VD / 128, T_LEN / 128), blk, 0, stream>>>(h, Wv, x,    T_LEN, VD,  DIM, 0);
  gemm_f32<<<dim3(VD / 128, T_LEN / 128), blk, 0, stream>>>(h, Wg, gate, T_LEN, VD,  DIM, 0);
  gemm_f32<<<dim3(256 / 128, T_LEN / 128), blk, 0, stream>>>(h, gen_w1, tg, T_LEN, 256, DIM, 1);
  proj_dyn<<<T_LEN, 256, 0, stream>>>(tg, gen_w2, dyn);
  proj_bg<<<T_LEN, 256, 0, stream>>>(h, Wb, Wa, A_log, dt_bias, beta, eg);
  // dynamic causal conv -> v
  conv_kernel<<<dim3(VD / 256, T_LEN), 256, 0, stream>>>(x, dyn, conv_w, v);
  // l2norm q (fold in DK^-0.5 = 1/16) and k
  l2norm_k<<<T_LEN * NH, 64, 0, stream>>>(q, 0.0625f);
  l2norm_k<<<T_LEN * NH, 64, 0, stream>>>(k, 1.0f);
  // gated delta-rule scan: o written into x buffer (dead after conv)
  scan_kernel<<<dim3(DVh / 16, NH), 256, 0, stream>>>(q, k, v, eg, beta, x);
  // gated RMSNorm: writes into gate buffer in place (same-index)
  norm_gate<<<T_LEN * NH, 256, 0, stream>>>(x, gate, norm_w, gate);
  // final projection
  gemm_f32<<<dim3(DIM / 128, T_LEN / 128), blk, 0, stream>>>(gate, Wo, out, T_LEN, DIM, VD, 0);
}

// Round 2
// 4705.309 us; speedup vs baseline: 1.1700x; 1.1700x over previous
//
#include <hip/hip_runtime.h>
#include <hip/hip_bf16.h>
#include <math.h>

#define T_LEN 4096
#define DIM   2048
#define NH    6
#define DK    256
#define DVh   512
#define KD    1536
#define VD    3072
#define CH    8
#define NCH   (T_LEN / CH)

__device__ __forceinline__ float silu_f(float v){ return v / (1.f + __expf(-v)); }

// ---------------- generic fp32 GEMM: C[M,N] = act(A[M,K] @ B[K,N]) ----------------
__global__ __launch_bounds__(256) void gemm_f32(
    const float* __restrict__ A, const float* __restrict__ B, float* __restrict__ C,
    int M, int N, int K, int act)
{
  __shared__ float As[16][128];
  __shared__ float Bs[16][128];
  const int bm = blockIdx.y * 128, bn = blockIdx.x * 128;
  const int tid = threadIdx.x;
  const int tx = tid & 15, ty = tid >> 4;
  float acc[8][8];
#pragma unroll
  for (int i = 0; i < 8; ++i)
#pragma unroll
    for (int j = 0; j < 8; ++j) acc[i][j] = 0.f;

  for (int k0 = 0; k0 < K; k0 += 16) {
#pragma unroll
    for (int i = 0; i < 2; ++i) {
      int li = tid * 2 + i;
      int row = li >> 2;
      int kc  = (li & 3) * 4;
      float4 a4 = *(const float4*)(A + (size_t)(bm + row) * K + k0 + kc);
      As[kc + 0][row] = a4.x; As[kc + 1][row] = a4.y;
      As[kc + 2][row] = a4.z; As[kc + 3][row] = a4.w;
      int kb = li >> 5;
      int nc = (li & 31) * 4;
      float4 b4 = *(const float4*)(B + (size_t)(k0 + kb) * N + bn + nc);
      *(float4*)&Bs[kb][nc] = b4;
    }
    __syncthreads();
#pragma unroll
    for (int kk = 0; kk < 16; ++kk) {
      float a[8], b[8];
#pragma unroll
      for (int i = 0; i < 8; ++i) a[i] = As[kk][ty * 8 + i];
#pragma unroll
      for (int j = 0; j < 8; ++j) b[j] = Bs[kk][tx * 8 + j];
#pragma unroll
      for (int i = 0; i < 8; ++i)
#pragma unroll
        for (int j = 0; j < 8; ++j) acc[i][j] += a[i] * b[j];
    }
    __syncthreads();
  }
#pragma unroll
  for (int i = 0; i < 8; ++i) {
    size_t row = (size_t)(bm + ty * 8 + i) * N + bn + tx * 8;
#pragma unroll
    for (int j = 0; j < 8; j += 4) {
      float4 o4;
      float v0 = acc[i][j], v1 = acc[i][j+1], v2 = acc[i][j+2], v3 = acc[i][j+3];
      if (act == 1) { v0 = silu_f(v0); v1 = silu_f(v1); v2 = silu_f(v2); v3 = silu_f(v3); }
      o4.x = v0; o4.y = v1; o4.z = v2; o4.w = v3;
      *(float4*)(C + row + j) = o4;
    }
  }
}

// ---------------- dyn = tg @ gen_w2 : [T,256]@[256,4] ----------------
__global__ __launch_bounds__(256) void proj_dyn(
    const float* __restrict__ tg, const float* __restrict__ w2, float* __restrict__ dyn)
{
  int t = blockIdx.x, tid = threadIdx.x;
  float g = tg[(size_t)t * 256 + tid];
  float p[4];
#pragma unroll
  for (int j = 0; j < 4; ++j) p[j] = g * w2[tid * 4 + j];
#pragma unroll
  for (int j = 0; j < 4; ++j)
    for (int m = 32; m >= 1; m >>= 1) p[j] += __shfl_xor(p[j], m);
  __shared__ float red[4][4];
  if ((tid & 63) == 0) {
    int w = tid >> 6;
#pragma unroll
    for (int j = 0; j < 4; ++j) red[w][j] = p[j];
  }
  __syncthreads();
  if (tid < 4) dyn[(size_t)t * 4 + tid] = red[0][tid] + red[1][tid] + red[2][tid] + red[3][tid];
}

// ---------------- beta / decay gate ----------------
__global__ __launch_bounds__(256) void proj_bg(
    const float* __restrict__ h, const float* __restrict__ Wb, const float* __restrict__ Wa,
    const float* __restrict__ A_log, const float* __restrict__ dt_bias,
    float* __restrict__ beta, float* __restrict__ eg)
{
  int t = blockIdx.x, tid = threadIdx.x;
  float pb[6], pa[6];
#pragma unroll
  for (int j = 0; j < 6; ++j) { pb[j] = 0.f; pa[j] = 0.f; }
  for (int d = tid; d < DIM; d += 256) {
    float hv = h[(size_t)t * DIM + d];
#pragma unroll
    for (int j = 0; j < 6; ++j) {
      pb[j] += hv * Wb[d * 6 + j];
      pa[j] += hv * Wa[d * 6 + j];
    }
  }
#pragma unroll
  for (int j = 0; j < 6; ++j)
    for (int m = 32; m >= 1; m >>= 1) { pb[j] += __shfl_xor(pb[j], m); pa[j] += __shfl_xor(pa[j], m); }
  __shared__ float rb[4][6], ra[4][6];
  if ((tid & 63) == 0) {
    int w = tid >> 6;
#pragma unroll
    for (int j = 0; j < 6; ++j) { rb[w][j] = pb[j]; ra[w][j] = pa[j]; }
  }
  __syncthreads();
  if (tid < 6) {
    int j = tid;
    float sb = rb[0][j] + rb[1][j] + rb[2][j] + rb[3][j];
    float sa = ra[0][j] + ra[1][j] + ra[2][j] + ra[3][j];
    beta[(size_t)t * 6 + j] = 1.f / (1.f + expf(-sb));
    float z = sa + dt_bias[j];
    float sp = (z > 20.f) ? z : log1pf(expf(z));
    eg[(size_t)t * 6 + j] = expf(-expf(A_log[j]) * sp);
  }
}

// ---------------- causal dynamic conv + silu ----------------
__global__ __launch_bounds__(256) void conv_kernel(
    const float* __restrict__ x, const float* __restrict__ dyn,
    const float* __restrict__ cw, float* __restrict__ v)
{
  int c = blockIdx.x * 256 + threadIdx.x;
  int t = blockIdx.y;
  float4 w4 = ((const float4*)cw)[c];
  float d0 = dyn[t * 4 + 0], d1 = dyn[t * 4 + 1], d2 = dyn[t * 4 + 2], d3 = dyn[t * 4 + 3];
  float acc = (w4.w + d3) * x[(size_t)t * VD + c];
  if (t >= 1) acc += (w4.z + d2) * x[(size_t)(t - 1) * VD + c];
  if (t >= 2) acc += (w4.y + d1) * x[(size_t)(t - 2) * VD + c];
  if (t >= 3) acc += (w4.x + d0) * x[(size_t)(t - 3) * VD + c];
  v[(size_t)t * VD + c] = silu_f(acc);
}

// ---------------- fused: l2norm(q)*scale, l2norm(k), qkd = qn . kn ----------------
__global__ __launch_bounds__(64) void l2norm_qk(
    float* __restrict__ q, float* __restrict__ k, float* __restrict__ qkd)
{
  size_t base = (size_t)blockIdx.x * 256;
  int tid = threadIdx.x;
  float4 qv = ((float4*)(q + base))[tid];
  float4 kv = ((float4*)(k + base))[tid];
  float sq = qv.x*qv.x + qv.y*qv.y + qv.z*qv.z + qv.w*qv.w;
  float sk = kv.x*kv.x + kv.y*kv.y + kv.z*kv.z + kv.w*kv.w;
  for (int m = 32; m >= 1; m >>= 1) { sq += __shfl_xor(sq, m); sk += __shfl_xor(sk, m); }
  float rq = rsqrtf(sq + 1e-6f) * 0.0625f;   // fold DK^-0.5
  float rk = rsqrtf(sk + 1e-6f);
  qv.x *= rq; qv.y *= rq; qv.z *= rq; qv.w *= rq;
  kv.x *= rk; kv.y *= rk; kv.z *= rk; kv.w *= rk;
  ((float4*)(q + base))[tid] = qv;
  ((float4*)(k + base))[tid] = kv;
  float d = qv.x*kv.x + qv.y*kv.y + qv.z*kv.z + qv.w*kv.w;
  for (int m = 32; m >= 1; m >>= 1) d += __shfl_xor(d, m);
  if (tid == 0) qkd[blockIdx.x] = d;
}

// ---------------- sequential gated delta-rule scan (LDS-chunked, fused output) ----------------
// grid (32, 6). 256 threads: col = tid>>4, sub = tid&15 owns state rows sub*16..sub*16+15.
// o_t = ee*(q.S_old) + dv*(q.k) -> only ONE cross-lane reduction pass per step.
__global__ __launch_bounds__(256) void scan_kernel(
    const float* __restrict__ Q, const float* __restrict__ K,
    const float* __restrict__ V, const float* __restrict__ EG,
    const float* __restrict__ BETA, const float* __restrict__ QKD,
    float* __restrict__ O)
{
  const int h  = blockIdx.y;
  const int cg = blockIdx.x;
  const int tid = threadIdx.x;
  const int col = tid >> 4;
  const int sub = tid & 15;
  const int c = cg * 16 + col;

  // skewed LDS: logical float d stored at d + 4*(d>>4)  (row = 320 floats)
  __shared__ float Kb[2][CH][320];
  __shared__ float Qb[2][CH][320];
  __shared__ float Vb[2][CH][16];
  __shared__ float4 Mb[2][CH];

  const int idxA = tid, idxB = tid + 256;
  const int rA = idxA >> 6, dA = idxA & 63;
  const int rB = idxB >> 6, dB = idxB & 63;
  const int pA = dA * 4 + 4 * (dA >> 2);
  const int pB = dB * 4 + 4 * (dB >> 2);

  float4 ka0, ka1, qa0, qa1, va;
  float mee = 0.f, mbb = 0.f, mqk = 0.f;

  auto issue_loads = [&](int ch) {
    int t0 = ch * CH;
    size_t sA = (size_t)(t0 + rA) * KD + h * 256 + dA * 4;
    size_t sB = (size_t)(t0 + rB) * KD + h * 256 + dB * 4;
    ka0 = *(const float4*)(K + sA); ka1 = *(const float4*)(K + sB);
    qa0 = *(const float4*)(Q + sA); qa1 = *(const float4*)(Q + sB);
    if (tid < 32)
      va = *(const float4*)(V + (size_t)(t0 + (tid >> 2)) * VD + h * DVh + cg * 16 + (tid & 3) * 4);
    if (tid < CH) {
      int t = t0 + tid;
      mee = EG[t * 6 + h]; mbb = BETA[t * 6 + h]; mqk = QKD[t * 6 + h];
    }
  };
  auto write_lds = [&](int buf) {
    *(float4*)&Kb[buf][rA][pA] = ka0;
    *(float4*)&Kb[buf][rB][pB] = ka1;
    *(float4*)&Qb[buf][rA][pA] = qa0;
    *(float4*)&Qb[buf][rB][pB] = qa1;
    if (tid < 32) *(float4*)&Vb[buf][tid >> 2][(tid & 3) * 4] = va;
    if (tid < CH) Mb[buf][tid] = make_float4(mee, mbb, mqk, 0.f);
  };

  float s[16];
#pragma unroll
  for (int i = 0; i < 16; ++i) s[i] = 0.f;

  issue_loads(0);
  write_lds(0);
  __syncthreads();

  float kr[2][16], qr[2][16], vv[2];
  float4 mm[2];
  const int sb = sub * 20;

  auto lds_pref = [&](int ph, int buf, int r) {
#pragma unroll
    for (int j = 0; j < 4; ++j) {
      *(float4*)&kr[ph][4 * j] = *(const float4*)&Kb[buf][r][sb + 4 * j];
      *(float4*)&qr[ph][4 * j] = *(const float4*)&Qb[buf][r][sb + 4 * j];
    }
    vv[ph] = Vb[buf][r][col];
    mm[ph] = Mb[buf][r];
  };

  int buf = 0;
  for (int ch = 0; ch < NCH; ++ch) {
    if (ch + 1 < NCH) issue_loads(ch + 1);   // global latency hidden under 8 steps
    lds_pref(0, buf, 0);
    const int t0 = ch * CH;
#pragma unroll
    for (int r = 0; r < CH; ++r) {
      const int ph = r & 1;
      if (r + 1 < CH) lds_pref(1 - ph, buf, r + 1);
      const float ee = mm[ph].x, bb = mm[ph].y, qk = mm[ph].z, v0 = vv[ph];
      // two 16-wide dot trees (4 accumulators, depth ~6)
      float p0 = 0.f, p1 = 0.f, p2 = 0.f, p3 = 0.f;
      float u0 = 0.f, u1 = 0.f, u2 = 0.f, u3 = 0.f;
#pragma unroll
      for (int i = 0; i < 4; ++i) {
        p0 += kr[ph][i]      * s[i];
        p1 += kr[ph][i + 4]  * s[i + 4];
        p2 += kr[ph][i + 8]  * s[i + 8];
        p3 += kr[ph][i + 12] * s[i + 12];
        u0 += qr[ph][i]      * s[i];
        u1 += qr[ph][i + 4]  * s[i + 4];
        u2 += qr[ph][i + 8]  * s[i + 8];
        u3 += qr[ph][i + 12] * s[i + 12];
      }
      float p_ = (p0 + p1) + (p2 + p3);
      float qs = (u0 + u1) + (u2 + u3);
      // single cross-lane pass, two values in flight
      p_ += __shfl_xor(p_, 1); qs += __shfl_xor(qs, 1);
      p_ += __shfl_xor(p_, 2); qs += __shfl_xor(qs, 2);
      p_ += __shfl_xor(p_, 4); qs += __shfl_xor(qs, 4);
      p_ += __shfl_xor(p_, 8); qs += __shfl_xor(qs, 8);
      const float dv = (v0 - ee * p_) * bb;
      const float oa = ee * qs + dv * qk;
#pragma unroll
      for (int i = 0; i < 16; ++i) s[i] = ee * s[i] + kr[ph][i] * dv;
      if (sub == 0) O[(size_t)(t0 + r) * VD + h * DVh + c] = oa;
    }
    if (ch + 1 < NCH) write_lds(buf ^ 1);
    __syncthreads();
    buf ^= 1;
  }
}

// ---------------- gated RMSNorm ----------------
__global__ __launch_bounds__(256) void norm_gate(
    const float* __restrict__ o, const float* __restrict__ gate,
    const float* __restrict__ nw, float* __restrict__ out)
{
  int th = blockIdx.x, tid = threadIdx.x;
  size_t base = (size_t)th * DVh;
  float x0 = o[base + tid], x1 = o[base + 256 + tid];
  float ss = x0 * x0 + x1 * x1;
  for (int m = 32; m >= 1; m >>= 1) ss += __shfl_xor(ss, m);
  __shared__ float red[4];
  if ((tid & 63) == 0) red[tid >> 6] = ss;
  __syncthreads();
  float rms = rsqrtf((red[0] + red[1] + red[2] + red[3]) * (1.f / 512.f) + 1e-5f);
  float g0 = gate[base + tid], g1 = gate[base + 256 + tid];
  out[base + tid]       = x0 * rms * nw[tid]       * silu_f(g0);
  out[base + 256 + tid] = x1 * rms * nw[tid + 256] * silu_f(g1);
}

extern "C" void kernel_launch(void* const* d_in, const int* in_sizes, int n_in,
                              void* d_out, int out_size, void* d_ws, size_t ws_size,
                              hipStream_t stream)
{
  const float* h       = (const float*)d_in[0];
  const float* Wq      = (const float*)d_in[1];
  const float* Wk      = (const float*)d_in[2];
  const float* Wv      = (const float*)d_in[3];
  const float* Wb      = (const float*)d_in[4];
  const float* Wa      = (const float*)d_in[5];
  const float* Wg      = (const float*)d_in[6];
  const float* Wo      = (const float*)d_in[7];
  const float* A_log   = (const float*)d_in[8];
  const float* dt_bias = (const float*)d_in[9];
  const float* conv_w  = (const float*)d_in[10];
  const float* gen_w1  = (const float*)d_in[11];
  const float* gen_w2  = (const float*)d_in[12];
  const float* norm_w  = (const float*)d_in[13];
  float* out = (float*)d_out;

  float* ws   = (float*)d_ws;
  float* q    = ws;
  float* k    = q    + (size_t)T_LEN * KD;
  float* x    = k    + (size_t)T_LEN * KD;
  float* v    = x    + (size_t)T_LEN * VD;
  float* gate = v    + (size_t)T_LEN * VD;
  float* tg   = gate + (size_t)T_LEN * VD;  // T*256; dead after proj_dyn
  float* dyn  = tg   + (size_t)T_LEN * 256;
  float* beta = dyn  + (size_t)T_LEN * 4;
  float* eg   = beta + (size_t)T_LEN * 6;
  float* qkd  = tg;                          // reuse tg (dead after proj_dyn)

  dim3 blk(256);
  gemm_f32<<<dim3(KD / 128, T_LEN / 128), blk, 0, stream>>>(h, Wq, q,    T_LEN, KD,  DIM, 1);
  gemm_f32<<<dim3(KD / 128, T_LEN / 128), blk, 0, stream>>>(h, Wk, k,    T_LEN, KD,  DIM, 1);
  gemm_f32<<<dim3(VD / 128, T_LEN / 128), blk, 0, stream>>>(h, Wv, x,    T_LEN, VD,  DIM, 0);
  gemm_f32<<<dim3(VD / 128, T_LEN / 128), blk, 0, stream>>>(h, Wg, gate, T_LEN, VD,  DIM, 0);
  gemm_f32<<<dim3(256 / 128, T_LEN / 128), blk, 0, stream>>>(h, gen_w1, tg, T_LEN, 256, DIM, 1);
  proj_dyn<<<T_LEN, 256, 0, stream>>>(tg, gen_w2, dyn);
  proj_bg<<<T_LEN, 256, 0, stream>>>(h, Wb, Wa, A_log, dt_bias, beta, eg);
  conv_kernel<<<dim3(VD / 256, T_LEN), 256, 0, stream>>>(x, dyn, conv_w, v);
  l2norm_qk<<<T_LEN * NH, 64, 0, stream>>>(q, k, qkd);
  scan_kernel<<<dim3(DVh / 16, NH), 256, 0, stream>>>(q, k, v, eg, beta, qkd, x);
  norm_gate<<<T_LEN * NH, 256, 0, stream>>>(x, gate, norm_w, gate);
  gemm_f32<<<dim3(DIM / 128, T_LEN / 128), blk, 0, stream>>>(gate, Wo, out, T_LEN, DIM, VD, 0);
}

// Round 3
// 1816.508 us; speedup vs baseline: 3.0306x; 2.5903x over previous
//
#include <hip/hip_runtime.h>
#include <hip/hip_bf16.h>
#include <math.h>

#define T_LEN 4096
#define DIM   2048
#define NH    6
#define DK    256
#define DVh   512
#define KD    1536
#define VD    3072
#define CH    8
#define NCH   (T_LEN / CH)

typedef __attribute__((ext_vector_type(8))) short bf16x8;
typedef __attribute__((ext_vector_type(4))) float f32x4;

__device__ __forceinline__ float silu_f(float v){ return v / (1.f + __expf(-v)); }

__device__ __forceinline__ unsigned short f2bf(float f) {
  unsigned int u = __float_as_uint(f);
  unsigned int r = u + 0x7FFFu + ((u >> 16) & 1u);
  return (unsigned short)(r >> 16);
}
__device__ __forceinline__ float bf2f(unsigned short s) {
  return __uint_as_float(((unsigned int)s) << 16);
}

// ---------------- cast fp32 -> bf16 (vectorized) ----------------
__global__ __launch_bounds__(256) void cast_bf16(
    const float* __restrict__ in, unsigned short* __restrict__ out)
{
  int i = blockIdx.x * 256 + threadIdx.x;
  float4 v4 = ((const float4*)in)[i];
  ushort4 o4;
  o4.x = f2bf(v4.x); o4.y = f2bf(v4.y); o4.z = f2bf(v4.z); o4.w = f2bf(v4.w);
  ((ushort4*)out)[i] = o4;
}

// ---------------- transpose + cast: in[R][Cn] fp32 -> out[Cn][R] bf16 ----------------
__global__ __launch_bounds__(256) void tcast(
    const float* __restrict__ in, unsigned short* __restrict__ out, int R, int Cn)
{
  __shared__ float tile[32][33];
  int bx = blockIdx.x * 32;  // col base in `in`
  int by = blockIdx.y * 32;  // row base in `in`
  int tx = threadIdx.x & 31, ty = threadIdx.x >> 5;  // 32 x 8
#pragma unroll
  for (int i = 0; i < 32; i += 8)
    tile[ty + i][tx] = in[(size_t)(by + ty + i) * Cn + bx + tx];
  __syncthreads();
#pragma unroll
  for (int i = 0; i < 32; i += 8)
    out[(size_t)(bx + ty + i) * R + by + tx] = f2bf(tile[tx][ty + i]);
}

// ---------------- bf16 MFMA GEMM: C[M,N] = act(A[M,K] @ BT[N,K]^T) ----------------
// m97 structure: 128x128 tile, BK=32, 4 waves 2x2, 16 mfma_16x16x32 per k-iter,
// global_load_lds width=16 staging. act: 0=fp32, 1=silu fp32, 2=bf16 store.
__global__ __launch_bounds__(256) void gemm_bt_bf16(
    const unsigned short* __restrict__ A, const unsigned short* __restrict__ BT,
    void* __restrict__ Cout, int M, int N, int K, int act)
{
  __shared__ unsigned short As[128 * 32];
  __shared__ unsigned short Bs[128 * 32];
  const int tid = threadIdx.x;
  const int bm = blockIdx.y * 128, bn = blockIdx.x * 128;
  const int lane = tid & 63, wave = tid >> 6;
  const int wm = (wave >> 1) * 64, wn = (wave & 1) * 64;
  const int fr = lane & 15, kq = lane >> 4;

  f32x4 acc[4][4];
#pragma unroll
  for (int i = 0; i < 4; ++i)
#pragma unroll
    for (int j = 0; j < 4; ++j) acc[i][j] = (f32x4){0.f, 0.f, 0.f, 0.f};

  const int r0 = tid >> 2, c0 = (tid & 3) * 8;  // 16B chunk coords; r1 = r0+64
  const int r1 = r0 + 64;

  for (int k0 = 0; k0 < K; k0 += 32) {
    __builtin_amdgcn_global_load_lds(
        (const __attribute__((address_space(1))) unsigned int*)(A + (size_t)(bm + r0) * K + k0 + c0),
        (__attribute__((address_space(3))) unsigned int*)(As + r0 * 32 + c0), 16, 0, 0);
    __builtin_amdgcn_global_load_lds(
        (const __attribute__((address_space(1))) unsigned int*)(A + (size_t)(bm + r1) * K + k0 + c0),
        (__attribute__((address_space(3))) unsigned int*)(As + r1 * 32 + c0), 16, 0, 0);
    __builtin_amdgcn_global_load_lds(
        (const __attribute__((address_space(1))) unsigned int*)(BT + (size_t)(bn + r0) * K + k0 + c0),
        (__attribute__((address_space(3))) unsigned int*)(Bs + r0 * 32 + c0), 16, 0, 0);
    __builtin_amdgcn_global_load_lds(
        (const __attribute__((address_space(1))) unsigned int*)(BT + (size_t)(bn + r1) * K + k0 + c0),
        (__attribute__((address_space(3))) unsigned int*)(Bs + r1 * 32 + c0), 16, 0, 0);
    __syncthreads();   // compiler emits s_waitcnt vmcnt(0) before barrier

    bf16x8 af[4], bfr[4];
#pragma unroll
    for (int i = 0; i < 4; ++i)
      af[i] = *(const bf16x8*)(As + (wm + i * 16 + fr) * 32 + kq * 8);
#pragma unroll
    for (int j = 0; j < 4; ++j)
      bfr[j] = *(const bf16x8*)(Bs + (wn + j * 16 + fr) * 32 + kq * 8);
#pragma unroll
    for (int i = 0; i < 4; ++i)
#pragma unroll
      for (int j = 0; j < 4; ++j)
        acc[i][j] = __builtin_amdgcn_mfma_f32_16x16x32_bf16(af[i], bfr[j], acc[i][j], 0, 0, 0);
    __syncthreads();
  }

  // C/D layout: col = lane&15, row = (lane>>4)*4 + reg  [measured m89/m91]
  if (act == 2) {
    unsigned short* C = (unsigned short*)Cout;
#pragma unroll
    for (int i = 0; i < 4; ++i) {
      int rbase = bm + wm + i * 16 + kq * 4;
#pragma unroll
      for (int r = 0; r < 4; ++r) {
        size_t rowoff = (size_t)(rbase + r) * N + bn + wn + fr;
#pragma unroll
        for (int j = 0; j < 4; ++j) C[rowoff + j * 16] = f2bf(acc[i][j][r]);
      }
    }
  } else {
    float* C = (float*)Cout;
#pragma unroll
    for (int i = 0; i < 4; ++i) {
      int rbase = bm + wm + i * 16 + kq * 4;
#pragma unroll
      for (int r = 0; r < 4; ++r) {
        size_t rowoff = (size_t)(rbase + r) * N + bn + wn + fr;
#pragma unroll
        for (int j = 0; j < 4; ++j) {
          float v = acc[i][j][r];
          if (act == 1) v = silu_f(v);
          C[rowoff + j * 16] = v;
        }
      }
    }
  }
}

// ---------------- dyn = tg @ gen_w2 : [T,256]@[256,4] ----------------
__global__ __launch_bounds__(256) void proj_dyn(
    const float* __restrict__ tg, const float* __restrict__ w2, float* __restrict__ dyn)
{
  int t = blockIdx.x, tid = threadIdx.x;
  float g = tg[(size_t)t * 256 + tid];
  float p[4];
#pragma unroll
  for (int j = 0; j < 4; ++j) p[j] = g * w2[tid * 4 + j];
#pragma unroll
  for (int j = 0; j < 4; ++j)
    for (int m = 32; m >= 1; m >>= 1) p[j] += __shfl_xor(p[j], m);
  __shared__ float red[4][4];
  if ((tid & 63) == 0) {
    int w = tid >> 6;
#pragma unroll
    for (int j = 0; j < 4; ++j) red[w][j] = p[j];
  }
  __syncthreads();
  if (tid < 4) dyn[(size_t)t * 4 + tid] = red[0][tid] + red[1][tid] + red[2][tid] + red[3][tid];
}

// ---------------- beta / decay gate ----------------
__global__ __launch_bounds__(256) void proj_bg(
    const float* __restrict__ h, const float* __restrict__ Wb, const float* __restrict__ Wa,
    const float* __restrict__ A_log, const float* __restrict__ dt_bias,
    float* __restrict__ beta, float* __restrict__ eg)
{
  int t = blockIdx.x, tid = threadIdx.x;
  float pb[6], pa[6];
#pragma unroll
  for (int j = 0; j < 6; ++j) { pb[j] = 0.f; pa[j] = 0.f; }
  for (int d = tid; d < DIM; d += 256) {
    float hv = h[(size_t)t * DIM + d];
#pragma unroll
    for (int j = 0; j < 6; ++j) {
      pb[j] += hv * Wb[d * 6 + j];
      pa[j] += hv * Wa[d * 6 + j];
    }
  }
#pragma unroll
  for (int j = 0; j < 6; ++j)
    for (int m = 32; m >= 1; m >>= 1) { pb[j] += __shfl_xor(pb[j], m); pa[j] += __shfl_xor(pa[j], m); }
  __shared__ float rb[4][6], ra[4][6];
  if ((tid & 63) == 0) {
    int w = tid >> 6;
#pragma unroll
    for (int j = 0; j < 6; ++j) { rb[w][j] = pb[j]; ra[w][j] = pa[j]; }
  }
  __syncthreads();
  if (tid < 6) {
    int j = tid;
    float sb = rb[0][j] + rb[1][j] + rb[2][j] + rb[3][j];
    float sa = ra[0][j] + ra[1][j] + ra[2][j] + ra[3][j];
    beta[(size_t)t * 6 + j] = 1.f / (1.f + expf(-sb));
    float z = sa + dt_bias[j];
    float sp = (z > 20.f) ? z : log1pf(expf(z));
    eg[(size_t)t * 6 + j] = expf(-expf(A_log[j]) * sp);
  }
}

// ---------------- causal dynamic conv + silu ----------------
__global__ __launch_bounds__(256) void conv_kernel(
    const float* __restrict__ x, const float* __restrict__ dyn,
    const float* __restrict__ cw, float* __restrict__ v)
{
  int c = blockIdx.x * 256 + threadIdx.x;
  int t = blockIdx.y;
  float4 w4 = ((const float4*)cw)[c];
  float d0 = dyn[t * 4 + 0], d1 = dyn[t * 4 + 1], d2 = dyn[t * 4 + 2], d3 = dyn[t * 4 + 3];
  float acc = (w4.w + d3) * x[(size_t)t * VD + c];
  if (t >= 1) acc += (w4.z + d2) * x[(size_t)(t - 1) * VD + c];
  if (t >= 2) acc += (w4.y + d1) * x[(size_t)(t - 2) * VD + c];
  if (t >= 3) acc += (w4.x + d0) * x[(size_t)(t - 3) * VD + c];
  v[(size_t)t * VD + c] = silu_f(acc);
}

// ---------------- fused: l2norm(q)*scale, l2norm(k), qkd = qn . kn ----------------
__global__ __launch_bounds__(64) void l2norm_qk(
    float* __restrict__ q, float* __restrict__ k, float* __restrict__ qkd)
{
  size_t base = (size_t)blockIdx.x * 256;
  int tid = threadIdx.x;
  float4 qv = ((float4*)(q + base))[tid];
  float4 kv = ((float4*)(k + base))[tid];
  float sq = qv.x*qv.x + qv.y*qv.y + qv.z*qv.z + qv.w*qv.w;
  float sk = kv.x*kv.x + kv.y*kv.y + kv.z*kv.z + kv.w*kv.w;
  for (int m = 32; m >= 1; m >>= 1) { sq += __shfl_xor(sq, m); sk += __shfl_xor(sk, m); }
  float rq = rsqrtf(sq + 1e-6f) * 0.0625f;   // fold DK^-0.5
  float rk = rsqrtf(sk + 1e-6f);
  qv.x *= rq; qv.y *= rq; qv.z *= rq; qv.w *= rq;
  kv.x *= rk; kv.y *= rk; kv.z *= rk; kv.w *= rk;
  ((float4*)(q + base))[tid] = qv;
  ((float4*)(k + base))[tid] = kv;
  float d = qv.x*kv.x + qv.y*kv.y + qv.z*kv.z + qv.w*kv.w;
  for (int m = 32; m >= 1; m >>= 1) d += __shfl_xor(d, m);
  if (tid == 0) qkd[blockIdx.x] = d;
}

// DPP row_ror butterfly add over 16-lane rows: every lane gets the row sum.
#define ROR_ADD(x, ctrl) \
  x += __int_as_float(__builtin_amdgcn_update_dpp(0, __float_as_int(x), ctrl, 0xF, 0xF, false))

// ---------------- sequential gated delta-rule scan ----------------
__global__ __launch_bounds__(256) void scan_kernel(
    const float* __restrict__ Q, const float* __restrict__ K,
    const float* __restrict__ V, const float* __restrict__ EG,
    const float* __restrict__ BETA, const float* __restrict__ QKD,
    float* __restrict__ O)
{
  const int h  = blockIdx.y;
  const int cg = blockIdx.x;
  const int tid = threadIdx.x;
  const int col = tid >> 4;
  const int sub = tid & 15;
  const int c = cg * 16 + col;

  __shared__ float Kb[2][CH][320];
  __shared__ float Qb[2][CH][320];
  __shared__ float Vb[2][CH][16];
  __shared__ float4 Mb[2][CH];

  const int idxA = tid, idxB = tid + 256;
  const int rA = idxA >> 6, dA = idxA & 63;
  const int rB = idxB >> 6, dB = idxB & 63;
  const int pA = dA * 4 + 4 * (dA >> 2);
  const int pB = dB * 4 + 4 * (dB >> 2);

  float4 ka0, ka1, qa0, qa1, va;
  float mee = 0.f, mbb = 0.f, mqk = 0.f;

  auto issue_loads = [&](int ch) {
    int t0 = ch * CH;
    size_t sA = (size_t)(t0 + rA) * KD + h * 256 + dA * 4;
    size_t sB = (size_t)(t0 + rB) * KD + h * 256 + dB * 4;
    ka0 = *(const float4*)(K + sA); ka1 = *(const float4*)(K + sB);
    qa0 = *(const float4*)(Q + sA); qa1 = *(const float4*)(Q + sB);
    if (tid < 32)
      va = *(const float4*)(V + (size_t)(t0 + (tid >> 2)) * VD + h * DVh + cg * 16 + (tid & 3) * 4);
    if (tid < CH) {
      int t = t0 + tid;
      mee = EG[t * 6 + h]; mbb = BETA[t * 6 + h]; mqk = QKD[t * 6 + h];
    }
  };
  auto write_lds = [&](int buf) {
    *(float4*)&Kb[buf][rA][pA] = ka0;
    *(float4*)&Kb[buf][rB][pB] = ka1;
    *(float4*)&Qb[buf][rA][pA] = qa0;
    *(float4*)&Qb[buf][rB][pB] = qa1;
    if (tid < 32) *(float4*)&Vb[buf][tid >> 2][(tid & 3) * 4] = va;
    if (tid < CH) Mb[buf][tid] = make_float4(mee, mbb, mqk, 0.f);
  };

  float s[16];
#pragma unroll
  for (int i = 0; i < 16; ++i) s[i] = 0.f;

  issue_loads(0);
  write_lds(0);
  __syncthreads();

  float kr[2][16], qr[2][16], vv[2];
  float4 mm[2];
  const int sb = sub * 20;

  auto lds_pref = [&](int ph, int buf, int r) {
#pragma unroll
    for (int j = 0; j < 4; ++j) {
      *(float4*)&kr[ph][4 * j] = *(const float4*)&Kb[buf][r][sb + 4 * j];
      *(float4*)&qr[ph][4 * j] = *(const float4*)&Qb[buf][r][sb + 4 * j];
    }
    vv[ph] = Vb[buf][r][col];
    mm[ph] = Mb[buf][r];
  };

  int buf = 0;
  for (int ch = 0; ch < NCH; ++ch) {
    if (ch + 1 < NCH) issue_loads(ch + 1);
    lds_pref(0, buf, 0);
    const int t0 = ch * CH;
#pragma unroll
    for (int r = 0; r < CH; ++r) {
      const int ph = r & 1;
      if (r + 1 < CH) lds_pref(1 - ph, buf, r + 1);
      const float ee = mm[ph].x, bb = mm[ph].y, qk = mm[ph].z, v0 = vv[ph];
      float p0 = 0.f, p1 = 0.f, p2 = 0.f, p3 = 0.f;
      float u0 = 0.f, u1 = 0.f, u2 = 0.f, u3 = 0.f;
#pragma unroll
      for (int i = 0; i < 4; ++i) {
        p0 += kr[ph][i]      * s[i];
        p1 += kr[ph][i + 4]  * s[i + 4];
        p2 += kr[ph][i + 8]  * s[i + 8];
        p3 += kr[ph][i + 12] * s[i + 12];
        u0 += qr[ph][i]      * s[i];
        u1 += qr[ph][i + 4]  * s[i + 4];
        u2 += qr[ph][i + 8]  * s[i + 8];
        u3 += qr[ph][i + 12] * s[i + 12];
      }
      float p_ = (p0 + p1) + (p2 + p3);
      float qs = (u0 + u1) + (u2 + u3);
      // DPP rotation butterfly (VALU-speed) instead of ds_bpermute shfls
      ROR_ADD(p_, 0x128); ROR_ADD(qs, 0x128);   // row_ror:8
      ROR_ADD(p_, 0x124); ROR_ADD(qs, 0x124);   // row_ror:4
      ROR_ADD(p_, 0x122); ROR_ADD(qs, 0x122);   // row_ror:2
      ROR_ADD(p_, 0x121); ROR_ADD(qs, 0x121);   // row_ror:1
      const float dv = (v0 - ee * p_) * bb;
      const float oa = ee * qs + dv * qk;
#pragma unroll
      for (int i = 0; i < 16; ++i) s[i] = ee * s[i] + kr[ph][i] * dv;
      if (sub == 0) O[(size_t)(t0 + r) * VD + h * DVh + c] = oa;
    }
    if (ch + 1 < NCH) write_lds(buf ^ 1);
    __syncthreads();
    buf ^= 1;
  }
}

// ---------------- gated RMSNorm: bf16 gate in, bf16 out (for final MFMA GEMM) ----------------
__global__ __launch_bounds__(256) void norm_gate(
    const float* __restrict__ o, const unsigned short* __restrict__ gate,
    const float* __restrict__ nw, unsigned short* __restrict__ out)
{
  int th = blockIdx.x, tid = threadIdx.x;
  size_t base = (size_t)th * DVh;
  float x0 = o[base + tid], x1 = o[base + 256 + tid];
  float ss = x0 * x0 + x1 * x1;
  for (int m = 32; m >= 1; m >>= 1) ss += __shfl_xor(ss, m);
  __shared__ float red[4];
  if ((tid & 63) == 0) red[tid >> 6] = ss;
  __syncthreads();
  float rms = rsqrtf((red[0] + red[1] + red[2] + red[3]) * (1.f / 512.f) + 1e-5f);
  float g0 = bf2f(gate[base + tid]), g1 = bf2f(gate[base + 256 + tid]);
  out[base + tid]       = f2bf(x0 * rms * nw[tid]       * silu_f(g0));
  out[base + 256 + tid] = f2bf(x1 * rms * nw[tid + 256] * silu_f(g1));
}

extern "C" void kernel_launch(void* const* d_in, const int* in_sizes, int n_in,
                              void* d_out, int out_size, void* d_ws, size_t ws_size,
                              hipStream_t stream)
{
  const float* h       = (const float*)d_in[0];
  const float* Wq      = (const float*)d_in[1];
  const float* Wk      = (const float*)d_in[2];
  const float* Wv      = (const float*)d_in[3];
  const float* Wb      = (const float*)d_in[4];
  const float* Wa      = (const float*)d_in[5];
  const float* Wg      = (const float*)d_in[6];
  const float* Wo      = (const float*)d_in[7];
  const float* A_log   = (const float*)d_in[8];
  const float* dt_bias = (const float*)d_in[9];
  const float* conv_w  = (const float*)d_in[10];
  const float* gen_w1  = (const float*)d_in[11];
  const float* gen_w2  = (const float*)d_in[12];
  const float* norm_w  = (const float*)d_in[13];
  float* out = (float*)d_out;

  float* ws   = (float*)d_ws;
  float* q    = ws;                            // T*KD
  float* k    = q    + (size_t)T_LEN * KD;
  float* x    = k    + (size_t)T_LEN * KD;     // T*VD (also o)
  float* v    = x    + (size_t)T_LEN * VD;
  float* tg   = v    + (size_t)T_LEN * VD;     // T*256
  float* dyn  = tg   + (size_t)T_LEN * 256;
  float* beta = dyn  + (size_t)T_LEN * 4;
  float* eg   = beta + (size_t)T_LEN * 6;
  float* fend = eg   + (size_t)T_LEN * 6;
  unsigned short* bh      = (unsigned short*)fend;              // T*DIM
  unsigned short* wT      = bh      + (size_t)T_LEN * DIM;      // max D*VD (reused per GEMM)
  unsigned short* gate_bf = wT      + (size_t)DIM * VD;         // T*VD
  unsigned short* go_bf   = gate_bf + (size_t)T_LEN * VD;       // T*VD
  float* qkd = tg;  // reuse: tg dead after proj_dyn, consumed before l2norm_qk

  dim3 blk(256);
  // h -> bf16
  cast_bf16<<<(T_LEN * DIM / 4) / 256, blk, 0, stream>>>(h, bh);
  // q = silu(h@Wq)
  tcast<<<dim3(KD / 32, DIM / 32), blk, 0, stream>>>(Wq, wT, DIM, KD);
  gemm_bt_bf16<<<dim3(KD / 128, T_LEN / 128), blk, 0, stream>>>(bh, wT, q, T_LEN, KD, DIM, 1);
  // k = silu(h@Wk)
  tcast<<<dim3(KD / 32, DIM / 32), blk, 0, stream>>>(Wk, wT, DIM, KD);
  gemm_bt_bf16<<<dim3(KD / 128, T_LEN / 128), blk, 0, stream>>>(bh, wT, k, T_LEN, KD, DIM, 1);
  // x = h@Wv
  tcast<<<dim3(VD / 32, DIM / 32), blk, 0, stream>>>(Wv, wT, DIM, VD);
  gemm_bt_bf16<<<dim3(VD / 128, T_LEN / 128), blk, 0, stream>>>(bh, wT, x, T_LEN, VD, DIM, 0);
  // gate = h@Wg (bf16 store)
  tcast<<<dim3(VD / 32, DIM / 32), blk, 0, stream>>>(Wg, wT, DIM, VD);
  gemm_bt_bf16<<<dim3(VD / 128, T_LEN / 128), blk, 0, stream>>>(bh, wT, gate_bf, T_LEN, VD, DIM, 2);
  // tg = silu(h@gen_w1)
  tcast<<<dim3(256 / 32, DIM / 32), blk, 0, stream>>>(gen_w1, wT, DIM, 256);
  gemm_bt_bf16<<<dim3(256 / 128, T_LEN / 128), blk, 0, stream>>>(bh, wT, tg, T_LEN, 256, DIM, 1);

  proj_dyn<<<T_LEN, blk, 0, stream>>>(tg, gen_w2, dyn);
  proj_bg<<<T_LEN, blk, 0, stream>>>(h, Wb, Wa, A_log, dt_bias, beta, eg);
  conv_kernel<<<dim3(VD / 256, T_LEN), blk, 0, stream>>>(x, dyn, conv_w, v);
  l2norm_qk<<<T_LEN * NH, 64, 0, stream>>>(q, k, qkd);
  scan_kernel<<<dim3(DVh / 16, NH), blk, 0, stream>>>(q, k, v, eg, beta, qkd, x);
  norm_gate<<<T_LEN * NH, blk, 0, stream>>>(x, gate_bf, norm_w, go_bf);
  // out = go @ Wo
  tcast<<<dim3(DIM / 32, VD / 32), blk, 0, stream>>>(Wo, wT, VD, DIM);
  gemm_bt_bf16<<<dim3(DIM / 128, T_LEN / 128), blk, 0, stream>>>(go_bf, wT, out, T_LEN, DIM, VD, 0);
}

// Round 4
// 1075.573 us; speedup vs baseline: 5.1184x; 1.6889x over previous
//
#include <hip/hip_runtime.h>
#include <hip/hip_bf16.h>
#include <math.h>

#define T_LEN 4096
#define DIM   2048
#define NH    6
#define DK    256
#define DVh   512
#define KD    1536
#define VD    3072
#define CK    64
#define NCHK  (T_LEN / CK)

typedef __attribute__((ext_vector_type(8))) short bf16x8;
typedef __attribute__((ext_vector_type(4))) float f32x4;

__device__ __forceinline__ float silu_f(float v){ return v / (1.f + __expf(-v)); }

__device__ __forceinline__ unsigned short f2bf(float f) {
  unsigned int u = __float_as_uint(f);
  unsigned int r = u + 0x7FFFu + ((u >> 16) & 1u);
  return (unsigned short)(r >> 16);
}
__device__ __forceinline__ float bf2f(unsigned short s) {
  return __uint_as_float(((unsigned int)s) << 16);
}

// ---------------- cast fp32 -> bf16 ----------------
__global__ __launch_bounds__(256) void cast_bf16(
    const float* __restrict__ in, unsigned short* __restrict__ out)
{
  int i = blockIdx.x * 256 + threadIdx.x;
  float4 v4 = ((const float4*)in)[i];
  ushort4 o4;
  o4.x = f2bf(v4.x); o4.y = f2bf(v4.y); o4.z = f2bf(v4.z); o4.w = f2bf(v4.w);
  ((ushort4*)out)[i] = o4;
}

// ---------------- transpose + cast: in[R][Cn] fp32 -> out[Cn][R] bf16 ----------------
__global__ __launch_bounds__(256) void tcast(
    const float* __restrict__ in, unsigned short* __restrict__ out, int R, int Cn)
{
  __shared__ float tile[32][33];
  int bx = blockIdx.x * 32;
  int by = blockIdx.y * 32;
  int tx = threadIdx.x & 31, ty = threadIdx.x >> 5;
#pragma unroll
  for (int i = 0; i < 32; i += 8)
    tile[ty + i][tx] = in[(size_t)(by + ty + i) * Cn + bx + tx];
  __syncthreads();
#pragma unroll
  for (int i = 0; i < 32; i += 8)
    out[(size_t)(bx + ty + i) * R + by + tx] = f2bf(tile[tx][ty + i]);
}

// ---------------- bf16 MFMA GEMM (m97 structure, validated R2/R3) ----------------
__global__ __launch_bounds__(256) void gemm_bt_bf16(
    const unsigned short* __restrict__ A, const unsigned short* __restrict__ BT,
    void* __restrict__ Cout, int M, int N, int K, int act)
{
  __shared__ unsigned short As[128 * 32];
  __shared__ unsigned short Bs[128 * 32];
  const int tid = threadIdx.x;
  const int bm = blockIdx.y * 128, bn = blockIdx.x * 128;
  const int lane = tid & 63, wave = tid >> 6;
  const int wm = (wave >> 1) * 64, wn = (wave & 1) * 64;
  const int fr = lane & 15, kq = lane >> 4;

  f32x4 acc[4][4];
#pragma unroll
  for (int i = 0; i < 4; ++i)
#pragma unroll
    for (int j = 0; j < 4; ++j) acc[i][j] = (f32x4){0.f, 0.f, 0.f, 0.f};

  const int r0 = tid >> 2, c0 = (tid & 3) * 8;
  const int r1 = r0 + 64;

  for (int k0 = 0; k0 < K; k0 += 32) {
    __builtin_amdgcn_global_load_lds(
        (const __attribute__((address_space(1))) unsigned int*)(A + (size_t)(bm + r0) * K + k0 + c0),
        (__attribute__((address_space(3))) unsigned int*)(As + r0 * 32 + c0), 16, 0, 0);
    __builtin_amdgcn_global_load_lds(
        (const __attribute__((address_space(1))) unsigned int*)(A + (size_t)(bm + r1) * K + k0 + c0),
        (__attribute__((address_space(3))) unsigned int*)(As + r1 * 32 + c0), 16, 0, 0);
    __builtin_amdgcn_global_load_lds(
        (const __attribute__((address_space(1))) unsigned int*)(BT + (size_t)(bn + r0) * K + k0 + c0),
        (__attribute__((address_space(3))) unsigned int*)(Bs + r0 * 32 + c0), 16, 0, 0);
    __builtin_amdgcn_global_load_lds(
        (const __attribute__((address_space(1))) unsigned int*)(BT + (size_t)(bn + r1) * K + k0 + c0),
        (__attribute__((address_space(3))) unsigned int*)(Bs + r1 * 32 + c0), 16, 0, 0);
    __syncthreads();

    bf16x8 af[4], bfr[4];
#pragma unroll
    for (int i = 0; i < 4; ++i)
      af[i] = *(const bf16x8*)(As + (wm + i * 16 + fr) * 32 + kq * 8);
#pragma unroll
    for (int j = 0; j < 4; ++j)
      bfr[j] = *(const bf16x8*)(Bs + (wn + j * 16 + fr) * 32 + kq * 8);
#pragma unroll
    for (int i = 0; i < 4; ++i)
#pragma unroll
      for (int j = 0; j < 4; ++j)
        acc[i][j] = __builtin_amdgcn_mfma_f32_16x16x32_bf16(af[i], bfr[j], acc[i][j], 0, 0, 0);
    __syncthreads();
  }

  if (act == 2) {
    unsigned short* C = (unsigned short*)Cout;
#pragma unroll
    for (int i = 0; i < 4; ++i) {
      int rbase = bm + wm + i * 16 + kq * 4;
#pragma unroll
      for (int r = 0; r < 4; ++r) {
        size_t rowoff = (size_t)(rbase + r) * N + bn + wn + fr;
#pragma unroll
        for (int j = 0; j < 4; ++j) C[rowoff + j * 16] = f2bf(acc[i][j][r]);
      }
    }
  } else {
    float* C = (float*)Cout;
#pragma unroll
    for (int i = 0; i < 4; ++i) {
      int rbase = bm + wm + i * 16 + kq * 4;
#pragma unroll
      for (int r = 0; r < 4; ++r) {
        size_t rowoff = (size_t)(rbase + r) * N + bn + wn + fr;
#pragma unroll
        for (int j = 0; j < 4; ++j) {
          float v = acc[i][j][r];
          if (act == 1) v = silu_f(v);
          C[rowoff + j * 16] = v;
        }
      }
    }
  }
}

// ---------------- dyn = tg @ gen_w2 ----------------
__global__ __launch_bounds__(256) void proj_dyn(
    const float* __restrict__ tg, const float* __restrict__ w2, float* __restrict__ dyn)
{
  int t = blockIdx.x, tid = threadIdx.x;
  float g = tg[(size_t)t * 256 + tid];
  float p[4];
#pragma unroll
  for (int j = 0; j < 4; ++j) p[j] = g * w2[tid * 4 + j];
#pragma unroll
  for (int j = 0; j < 4; ++j)
    for (int m = 32; m >= 1; m >>= 1) p[j] += __shfl_xor(p[j], m);
  __shared__ float red[4][4];
  if ((tid & 63) == 0) {
    int w = tid >> 6;
#pragma unroll
    for (int j = 0; j < 4; ++j) red[w][j] = p[j];
  }
  __syncthreads();
  if (tid < 4) dyn[(size_t)t * 4 + tid] = red[0][tid] + red[1][tid] + red[2][tid] + red[3][tid];
}

// ---------------- beta / raw decay log-gate g ----------------
__global__ __launch_bounds__(256) void proj_bg(
    const float* __restrict__ h, const float* __restrict__ Wb, const float* __restrict__ Wa,
    const float* __restrict__ A_log, const float* __restrict__ dt_bias,
    float* __restrict__ beta, float* __restrict__ gout)
{
  int t = blockIdx.x, tid = threadIdx.x;
  float pb[6], pa[6];
#pragma unroll
  for (int j = 0; j < 6; ++j) { pb[j] = 0.f; pa[j] = 0.f; }
  for (int d = tid; d < DIM; d += 256) {
    float hv = h[(size_t)t * DIM + d];
#pragma unroll
    for (int j = 0; j < 6; ++j) {
      pb[j] += hv * Wb[d * 6 + j];
      pa[j] += hv * Wa[d * 6 + j];
    }
  }
#pragma unroll
  for (int j = 0; j < 6; ++j)
    for (int m = 32; m >= 1; m >>= 1) { pb[j] += __shfl_xor(pb[j], m); pa[j] += __shfl_xor(pa[j], m); }
  __shared__ float rb[4][6], ra[4][6];
  if ((tid & 63) == 0) {
    int w = tid >> 6;
#pragma unroll
    for (int j = 0; j < 6; ++j) { rb[w][j] = pb[j]; ra[w][j] = pa[j]; }
  }
  __syncthreads();
  if (tid < 6) {
    int j = tid;
    float sb = rb[0][j] + rb[1][j] + rb[2][j] + rb[3][j];
    float sa = ra[0][j] + ra[1][j] + ra[2][j] + ra[3][j];
    beta[(size_t)t * 6 + j] = 1.f / (1.f + expf(-sb));
    float z = sa + dt_bias[j];
    float sp = (z > 20.f) ? z : log1pf(expf(z));
    gout[(size_t)t * 6 + j] = -expf(A_log[j]) * sp;   // raw log-gate (g < 0)
  }
}

// ---------------- causal dynamic conv + silu ----------------
__global__ __launch_bounds__(256) void conv_kernel(
    const float* __restrict__ x, const float* __restrict__ dyn,
    const float* __restrict__ cw, float* __restrict__ v)
{
  int c = blockIdx.x * 256 + threadIdx.x;
  int t = blockIdx.y;
  float4 w4 = ((const float4*)cw)[c];
  float d0 = dyn[t * 4 + 0], d1 = dyn[t * 4 + 1], d2 = dyn[t * 4 + 2], d3 = dyn[t * 4 + 3];
  float acc = (w4.w + d3) * x[(size_t)t * VD + c];
  if (t >= 1) acc += (w4.z + d2) * x[(size_t)(t - 1) * VD + c];
  if (t >= 2) acc += (w4.y + d1) * x[(size_t)(t - 2) * VD + c];
  if (t >= 3) acc += (w4.x + d0) * x[(size_t)(t - 3) * VD + c];
  v[(size_t)t * VD + c] = silu_f(acc);
}

// ---------------- l2norm(q)*scale, l2norm(k) in place ----------------
__global__ __launch_bounds__(64) void l2norm_qk(
    float* __restrict__ q, float* __restrict__ k)
{
  size_t base = (size_t)blockIdx.x * 256;
  int tid = threadIdx.x;
  float4 qv = ((float4*)(q + base))[tid];
  float4 kv = ((float4*)(k + base))[tid];
  float sq = qv.x*qv.x + qv.y*qv.y + qv.z*qv.z + qv.w*qv.w;
  float sk = kv.x*kv.x + kv.y*kv.y + kv.z*kv.z + kv.w*kv.w;
  for (int m = 32; m >= 1; m >>= 1) { sq += __shfl_xor(sq, m); sk += __shfl_xor(sk, m); }
  float rq = rsqrtf(sq + 1e-6f) * 0.0625f;   // fold DK^-0.5
  float rk = rsqrtf(sk + 1e-6f);
  qv.x *= rq; qv.y *= rq; qv.z *= rq; qv.w *= rq;
  kv.x *= rk; kv.y *= rk; kv.z *= rk; kv.w *= rk;
  ((float4*)(q + base))[tid] = qv;
  ((float4*)(k + base))[tid] = kv;
}

// ---------------- P1: within-chunk inclusive cumsum of g, gamma = exp(c_end) ----------------
__global__ __launch_bounds__(64) void cumsum_g(
    const float* __restrict__ g, float* __restrict__ c, float* __restrict__ gammas)
{
  int ch = blockIdx.x, h = blockIdx.y;
  int t0 = ch * CK;
  int lane = threadIdx.x;
  float cum = g[(size_t)(t0 + lane) * 6 + h];
  for (int off = 1; off < 64; off <<= 1) {
    float n = __shfl_up(cum, off);
    if (lane >= off) cum += n;
  }
  c[(size_t)h * T_LEN + t0 + lane] = cum;
  if (lane == 63) gammas[h * NCHK + ch] = __expf(cum);
}

// ---------------- P2a: Kbar/Qbar = exp(c_t) * {k,q}  (bf16, same layout) ----------------
__global__ __launch_bounds__(384) void scale_kq(
    const float* __restrict__ q, const float* __restrict__ k, const float* __restrict__ c,
    unsigned short* __restrict__ Qb, unsigned short* __restrict__ Kb)
{
  int t = blockIdx.x;
  int tid = threadIdx.x;           // float4 index within row (384 = KD/4)
  int h = tid >> 6;
  float w1 = __expf(c[(size_t)h * T_LEN + t]);
  size_t off = (size_t)t * KD + tid * 4;
  float4 qv = *(const float4*)(q + off);
  float4 kv = *(const float4*)(k + off);
  ushort4 qo, ko;
  qo.x = f2bf(w1 * qv.x); qo.y = f2bf(w1 * qv.y); qo.z = f2bf(w1 * qv.z); qo.w = f2bf(w1 * qv.w);
  ko.x = f2bf(w1 * kv.x); ko.y = f2bf(w1 * kv.y); ko.z = f2bf(w1 * kv.z); ko.w = f2bf(w1 * kv.w);
  *(ushort4*)(Qb + off) = qo;
  *(ushort4*)(Kb + off) = ko;
}

// ---------------- P2b: KhT[h][ch][kk][tt] = exp(c_end - c_t) * k[t][kk]  (bf16) ----------------
__global__ __launch_bounds__(256) void make_khT(
    const float* __restrict__ k, const float* __restrict__ c,
    unsigned short* __restrict__ KhT)
{
  int ch = blockIdx.x, h = blockIdx.y;
  int t0 = ch * CK;
  int tt = threadIdx.x & 63, ks = threadIdx.x >> 6;
  float cend = c[(size_t)h * T_LEN + t0 + 63];
  float w2 = __expf(cend - c[(size_t)h * T_LEN + t0 + tt]);
  size_t obase = ((size_t)(h * NCHK + ch)) * DK * CK;
#pragma unroll 8
  for (int kb2 = 0; kb2 < 64; ++kb2) {
    int kk = ks * 64 + kb2;
    float kv = k[(size_t)(t0 + tt) * KD + h * 256 + kk];
    KhT[obase + (size_t)kk * CK + tt] = f2bf(w2 * kv);
  }
}

// ---------------- P3: per (h,chunk): L = strict_tril(beta_t e^{c_t-c_j} k_t.k_j),
//                   P = tril(e^{c_t-c_j} q_t.k_j)  via MFMA ----------------
__global__ __launch_bounds__(256) void chunk_lp(
    const float* __restrict__ q, const float* __restrict__ k,
    const float* __restrict__ c, const float* __restrict__ beta,
    float* __restrict__ Lg, unsigned short* __restrict__ Pm)
{
  const int ch = blockIdx.x, h = blockIdx.y;
  const int t0 = ch * CK;
  const int tid = threadIdx.x;
  const int w = tid >> 6, lane = tid & 63, fr = lane & 15, kq = lane >> 4;
  __shared__ unsigned short kb[64][264];
  __shared__ unsigned short qb[64][264];
  __shared__ float cs[64], bs[64];
#pragma unroll
  for (int i = 0; i < 16; ++i) {
    int fi = tid + i * 256;
    int r = fi >> 6, d4 = fi & 63;
    float4 kv = *(const float4*)(k + (size_t)(t0 + r) * KD + h * 256 + d4 * 4);
    float4 qv = *(const float4*)(q + (size_t)(t0 + r) * KD + h * 256 + d4 * 4);
    ushort4 k4, q4;
    k4.x = f2bf(kv.x); k4.y = f2bf(kv.y); k4.z = f2bf(kv.z); k4.w = f2bf(kv.w);
    q4.x = f2bf(qv.x); q4.y = f2bf(qv.y); q4.z = f2bf(qv.z); q4.w = f2bf(qv.w);
    *(ushort4*)&kb[r][d4 * 4] = k4;
    *(ushort4*)&qb[r][d4 * 4] = q4;
  }
  if (tid < 64) {
    cs[tid] = c[(size_t)h * T_LEN + t0 + tid];
    bs[tid] = beta[(size_t)(t0 + tid) * 6 + h];
  }
  __syncthreads();

  f32x4 akk[4], aqk[4];
#pragma unroll
  for (int j = 0; j < 4; ++j) { akk[j] = (f32x4){0,0,0,0}; aqk[j] = (f32x4){0,0,0,0}; }
#pragma unroll
  for (int kt = 0; kt < 8; ++kt) {
    bf16x8 ak = *(const bf16x8*)&kb[16 * w + fr][kt * 32 + kq * 8];
    bf16x8 aq = *(const bf16x8*)&qb[16 * w + fr][kt * 32 + kq * 8];
#pragma unroll
    for (int j = 0; j < 4; ++j) {
      bf16x8 b = *(const bf16x8*)&kb[j * 16 + fr][kt * 32 + kq * 8];
      akk[j] = __builtin_amdgcn_mfma_f32_16x16x32_bf16(ak, b, akk[j], 0, 0, 0);
      aqk[j] = __builtin_amdgcn_mfma_f32_16x16x32_bf16(aq, b, aqk[j], 0, 0, 0);
    }
  }
  size_t base = ((size_t)(h * NCHK + ch)) * CK * CK;
#pragma unroll
  for (int j = 0; j < 4; ++j) {
#pragma unroll
    for (int r = 0; r < 4; ++r) {
      int t = 16 * w + kq * 4 + r, col = j * 16 + fr;
      float e = __expf(fminf(cs[t] - cs[col], 0.f));
      Lg[base + t * 64 + col] = (col < t) ? bs[t] * e * akk[j][r] : 0.f;
      Pm[base + t * 64 + col] = f2bf((col <= t) ? e * aqk[j][r] : 0.f);
    }
  }
}

// ---------------- P4: T' = (I+L)^{-1} diag(beta)  (bf16) ----------------
__global__ __launch_bounds__(64) void tri_inv(
    const float* __restrict__ Lg, const float* __restrict__ beta,
    unsigned short* __restrict__ Tm)
{
  const int ch = blockIdx.x, h = blockIdx.y;
  const size_t base = ((size_t)(h * NCHK + ch)) * CK * CK;
  const int j = threadIdx.x;
  __shared__ float Ll[64][65];
  __shared__ float Tl[64][65];
  for (int t = 0; t < 64; ++t) Ll[t][j] = Lg[base + t * 64 + j];
  __syncthreads();
  for (int t = 0; t < 64; ++t) {
    float s;
    if (j > t) s = 0.f;
    else if (j == t) s = 1.f;
    else {
      s = 0.f;
      for (int m = j; m < t; ++m) s -= Ll[t][m] * Tl[m][j];
    }
    Tl[t][j] = s;
  }
  float bj = beta[(size_t)(ch * 64 + j) * 6 + h];
  for (int t = 0; t < 64; ++t) Tm[base + t * 64 + j] = f2bf(Tl[t][j] * bj);
}

// ---------------- chunked gated delta-rule scan (MFMA) ----------------
// grid (32, 6): blockIdx.x = 16-col slice of DVh, blockIdx.y = head.
// State S[256][16] fp32 lives in MFMA accumulators: wave w owns rows 64w..64w+63
// (4 tiles of 16); lane holds rows kq*4+reg of its tile at col fr.
__global__ __launch_bounds__(256) void scan_chunk(
    const unsigned short* __restrict__ Kb,   // [T][KD] Kbar
    const unsigned short* __restrict__ Qb,   // [T][KD] Qbar
    const unsigned short* __restrict__ KhT,  // [H][NCHK][DK][CK]
    const unsigned short* __restrict__ Tm,   // [H][NCHK][CK][CK]
    const unsigned short* __restrict__ Pm,   // [H][NCHK][CK][CK]
    const float* __restrict__ gammas,        // [H][NCHK]
    float* __restrict__ VO)                  // [T][VD]: V in, O out (in place)
{
  const int h = blockIdx.y, sl = blockIdx.x;
  const int tid = threadIdx.x;
  const int w = tid >> 6, lane = tid & 63;
  const int fr = lane & 15, kq = lane >> 4;

  __shared__ unsigned short S0h[16][264];
  __shared__ unsigned short S0l[16][264];
  __shared__ unsigned short XT[16][72];
  __shared__ unsigned short DVT[16][72];

  f32x4 st[4];
#pragma unroll
  for (int i = 0; i < 4; ++i) st[i] = (f32x4){0.f, 0.f, 0.f, 0.f};

  const int colg = h * DVh + sl * 16 + fr;
  const size_t hc0 = (size_t)h * NCHK;

  for (int ch = 0; ch < NCHK; ++ch) {
    const int t0 = ch * CK;
    const size_t cb = hc0 + ch;

    // --- global fragment loads (off the LDS dependency) ---
    bf16x8 kf[8], qf[8];
    {
      const unsigned short* krow = Kb + (size_t)(t0 + 16 * w + fr) * KD + h * 256 + kq * 8;
      const unsigned short* qrow = Qb + (size_t)(t0 + 16 * w + fr) * KD + h * 256 + kq * 8;
#pragma unroll
      for (int kt = 0; kt < 8; ++kt) {
        kf[kt] = *(const bf16x8*)(krow + kt * 32);
        qf[kt] = *(const bf16x8*)(qrow + kt * 32);
      }
    }
    bf16x8 tf[2], pf[2];
    {
      const unsigned short* trow = Tm + (cb * CK + 16 * w + fr) * CK + kq * 8;
      const unsigned short* prow = Pm + (cb * CK + 16 * w + fr) * CK + kq * 8;
      tf[0] = *(const bf16x8*)(trow); tf[1] = *(const bf16x8*)(trow + 32);
      pf[0] = *(const bf16x8*)(prow); pf[1] = *(const bf16x8*)(prow + 32);
    }
    bf16x8 hf[4][2];
#pragma unroll
    for (int i = 0; i < 4; ++i) {
      const unsigned short* hrow = KhT + (cb * DK + 64 * w + 16 * i + fr) * CK + kq * 8;
      hf[i][0] = *(const bf16x8*)(hrow); hf[i][1] = *(const bf16x8*)(hrow + 32);
    }
    float vld[4];
#pragma unroll
    for (int r = 0; r < 4; ++r)
      vld[r] = VO[(size_t)(t0 + 16 * w + kq * 4 + r) * VD + colg];
    const float gam = gammas[hc0 + ch];

    // --- stage S0 to LDS as bf16 hi+lo ---
#pragma unroll
    for (int i = 0; i < 4; ++i) {
      ushort4 hi4, lo4;
      {
        float s0 = st[i][0], s1 = st[i][1], s2 = st[i][2], s3 = st[i][3];
        hi4.x = f2bf(s0); lo4.x = f2bf(s0 - bf2f(hi4.x));
        hi4.y = f2bf(s1); lo4.y = f2bf(s1 - bf2f(hi4.y));
        hi4.z = f2bf(s2); lo4.z = f2bf(s2 - bf2f(hi4.z));
        hi4.w = f2bf(s3); lo4.w = f2bf(s3 - bf2f(hi4.w));
      }
      *(ushort4*)&S0h[fr][64 * w + 16 * i + kq * 4] = hi4;
      *(ushort4*)&S0l[fr][64 * w + 16 * i + kq * 4] = lo4;
    }
    __syncthreads();

    // --- step 1: Y = Kbar S0 (hi+lo);  X = V - Y -> bf16 XT ---
    {
      f32x4 y = (f32x4){0.f, 0.f, 0.f, 0.f};
#pragma unroll
      for (int kt = 0; kt < 8; ++kt) {
        bf16x8 bh_ = *(const bf16x8*)&S0h[fr][kt * 32 + kq * 8];
        bf16x8 bl_ = *(const bf16x8*)&S0l[fr][kt * 32 + kq * 8];
        y = __builtin_amdgcn_mfma_f32_16x16x32_bf16(kf[kt], bh_, y, 0, 0, 0);
        y = __builtin_amdgcn_mfma_f32_16x16x32_bf16(kf[kt], bl_, y, 0, 0, 0);
      }
      ushort4 x4;
      x4.x = f2bf(vld[0] - y[0]); x4.y = f2bf(vld[1] - y[1]);
      x4.z = f2bf(vld[2] - y[2]); x4.w = f2bf(vld[3] - y[3]);
      *(ushort4*)&XT[fr][16 * w + kq * 4] = x4;
    }
    __syncthreads();

    // --- step 2: DV = T' X -> bf16 DVT ---
    {
      f32x4 d = (f32x4){0.f, 0.f, 0.f, 0.f};
#pragma unroll
      for (int kt = 0; kt < 2; ++kt) {
        bf16x8 b = *(const bf16x8*)&XT[fr][kt * 32 + kq * 8];
        d = __builtin_amdgcn_mfma_f32_16x16x32_bf16(tf[kt], b, d, 0, 0, 0);
      }
      ushort4 d4;
      d4.x = f2bf(d[0]); d4.y = f2bf(d[1]); d4.z = f2bf(d[2]); d4.w = f2bf(d[3]);
      *(ushort4*)&DVT[fr][16 * w + kq * 4] = d4;
    }
    __syncthreads();

    // --- step 3: O = Qbar S0 + P DV ---
    {
      f32x4 o = (f32x4){0.f, 0.f, 0.f, 0.f};
#pragma unroll
      for (int kt = 0; kt < 8; ++kt) {
        bf16x8 bh_ = *(const bf16x8*)&S0h[fr][kt * 32 + kq * 8];
        bf16x8 bl_ = *(const bf16x8*)&S0l[fr][kt * 32 + kq * 8];
        o = __builtin_amdgcn_mfma_f32_16x16x32_bf16(qf[kt], bh_, o, 0, 0, 0);
        o = __builtin_amdgcn_mfma_f32_16x16x32_bf16(qf[kt], bl_, o, 0, 0, 0);
      }
#pragma unroll
      for (int kt = 0; kt < 2; ++kt) {
        bf16x8 b = *(const bf16x8*)&DVT[fr][kt * 32 + kq * 8];
        o = __builtin_amdgcn_mfma_f32_16x16x32_bf16(pf[kt], b, o, 0, 0, 0);
      }
#pragma unroll
      for (int r = 0; r < 4; ++r)
        VO[(size_t)(t0 + 16 * w + kq * 4 + r) * VD + colg] = o[r];
    }

    // --- step 4: S = gamma*S0 + Khat^T DV ---
#pragma unroll
    for (int i = 0; i < 4; ++i) {
      st[i][0] *= gam; st[i][1] *= gam; st[i][2] *= gam; st[i][3] *= gam;
#pragma unroll
      for (int kt = 0; kt < 2; ++kt) {
        bf16x8 b = *(const bf16x8*)&DVT[fr][kt * 32 + kq * 8];
        st[i] = __builtin_amdgcn_mfma_f32_16x16x32_bf16(hf[i][kt], b, st[i], 0, 0, 0);
      }
    }
    __syncthreads();
  }
}

// ---------------- gated RMSNorm ----------------
__global__ __launch_bounds__(256) void norm_gate(
    const float* __restrict__ o, const unsigned short* __restrict__ gate,
    const float* __restrict__ nw, unsigned short* __restrict__ out)
{
  int th = blockIdx.x, tid = threadIdx.x;
  size_t base = (size_t)th * DVh;
  float x0 = o[base + tid], x1 = o[base + 256 + tid];
  float ss = x0 * x0 + x1 * x1;
  for (int m = 32; m >= 1; m >>= 1) ss += __shfl_xor(ss, m);
  __shared__ float red[4];
  if ((tid & 63) == 0) red[tid >> 6] = ss;
  __syncthreads();
  float rms = rsqrtf((red[0] + red[1] + red[2] + red[3]) * (1.f / 512.f) + 1e-5f);
  float g0 = bf2f(gate[base + tid]), g1 = bf2f(gate[base + 256 + tid]);
  out[base + tid]       = f2bf(x0 * rms * nw[tid]       * silu_f(g0));
  out[base + 256 + tid] = f2bf(x1 * rms * nw[tid + 256] * silu_f(g1));
}

extern "C" void kernel_launch(void* const* d_in, const int* in_sizes, int n_in,
                              void* d_out, int out_size, void* d_ws, size_t ws_size,
                              hipStream_t stream)
{
  const float* h       = (const float*)d_in[0];
  const float* Wq      = (const float*)d_in[1];
  const float* Wk      = (const float*)d_in[2];
  const float* Wv      = (const float*)d_in[3];
  const float* Wb      = (const float*)d_in[4];
  const float* Wa      = (const float*)d_in[5];
  const float* Wg      = (const float*)d_in[6];
  const float* Wo      = (const float*)d_in[7];
  const float* A_log   = (const float*)d_in[8];
  const float* dt_bias = (const float*)d_in[9];
  const float* conv_w  = (const float*)d_in[10];
  const float* gen_w1  = (const float*)d_in[11];
  const float* gen_w2  = (const float*)d_in[12];
  const float* norm_w  = (const float*)d_in[13];
  float* out = (float*)d_out;

  const size_t TK = (size_t)T_LEN * KD, TV = (size_t)T_LEN * VD, TD = (size_t)T_LEN * DIM;

  float* ws   = (float*)d_ws;
  float* q    = ws;
  float* k    = q    + TK;
  float* x    = k    + TK;          // h@Wv conv input; region later reused (see aliases)
  float* v    = x    + TV;          // conv out; O written in place by scan
  float* tg   = v    + TV;          // T*256
  float* dyn  = tg   + (size_t)T_LEN * 256;
  float* beta = dyn  + (size_t)T_LEN * 4;
  float* g    = beta + (size_t)T_LEN * 6;
  float* c    = g    + (size_t)T_LEN * 6;       // [H][T]
  float* gam  = c    + (size_t)NH * T_LEN;      // [H][NCHK]
  float* fend = gam  + 512;
  unsigned short* bh      = (unsigned short*)fend;          // T*DIM
  unsigned short* wT      = bh      + TD;                   // DIM*VD
  unsigned short* gate_bf = wT      + (size_t)DIM * VD;     // T*VD
  unsigned short* go_bf   = gate_bf + TV;                   // T*VD
  // aliases (lifetime-disjoint):
  unsigned short* Kb_s  = bh;                 // Kbar: bh dead after projection GEMMs
  unsigned short* Qb_s  = (unsigned short*)x; // x region free after conv
  unsigned short* KhT_s = Qb_s + TK;
  unsigned short* Tm_s  = KhT_s + TK;         // H*NCHK*DK*CK == T*KD
  unsigned short* Pm_s  = Tm_s + (size_t)NH * NCHK * CK * CK;
  float* Lg = (float*)go_bf;                  // consumed before norm_gate writes go_bf

  dim3 blk(256);
  cast_bf16<<<(TD / 4) / 256, blk, 0, stream>>>(h, bh);
  tcast<<<dim3(KD / 32, DIM / 32), blk, 0, stream>>>(Wq, wT, DIM, KD);
  gemm_bt_bf16<<<dim3(KD / 128, T_LEN / 128), blk, 0, stream>>>(bh, wT, q, T_LEN, KD, DIM, 1);
  tcast<<<dim3(KD / 32, DIM / 32), blk, 0, stream>>>(Wk, wT, DIM, KD);
  gemm_bt_bf16<<<dim3(KD / 128, T_LEN / 128), blk, 0, stream>>>(bh, wT, k, T_LEN, KD, DIM, 1);
  tcast<<<dim3(VD / 32, DIM / 32), blk, 0, stream>>>(Wv, wT, DIM, VD);
  gemm_bt_bf16<<<dim3(VD / 128, T_LEN / 128), blk, 0, stream>>>(bh, wT, x, T_LEN, VD, DIM, 0);
  tcast<<<dim3(VD / 32, DIM / 32), blk, 0, stream>>>(Wg, wT, DIM, VD);
  gemm_bt_bf16<<<dim3(VD / 128, T_LEN / 128), blk, 0, stream>>>(bh, wT, gate_bf, T_LEN, VD, DIM, 2);
  tcast<<<dim3(256 / 32, DIM / 32), blk, 0, stream>>>(gen_w1, wT, DIM, 256);
  gemm_bt_bf16<<<dim3(256 / 128, T_LEN / 128), blk, 0, stream>>>(bh, wT, tg, T_LEN, 256, DIM, 1);

  proj_dyn<<<T_LEN, blk, 0, stream>>>(tg, gen_w2, dyn);
  proj_bg<<<T_LEN, blk, 0, stream>>>(h, Wb, Wa, A_log, dt_bias, beta, g);
  conv_kernel<<<dim3(VD / 256, T_LEN), blk, 0, stream>>>(x, dyn, conv_w, v);
  l2norm_qk<<<T_LEN * NH, 64, 0, stream>>>(q, k);

  cumsum_g<<<dim3(NCHK, NH), 64, 0, stream>>>(g, c, gam);
  scale_kq<<<T_LEN, 384, 0, stream>>>(q, k, c, Qb_s, Kb_s);
  make_khT<<<dim3(NCHK, NH), blk, 0, stream>>>(k, c, KhT_s);
  chunk_lp<<<dim3(NCHK, NH), blk, 0, stream>>>(q, k, c, beta, Lg, Pm_s);
  tri_inv<<<dim3(NCHK, NH), 64, 0, stream>>>(Lg, beta, Tm_s);

  scan_chunk<<<dim3(DVh / 16, NH), blk, 0, stream>>>(Kb_s, Qb_s, KhT_s, Tm_s, Pm_s, gam, v);

  norm_gate<<<T_LEN * NH, blk, 0, stream>>>(v, gate_bf, norm_w, go_bf);
  tcast<<<dim3(DIM / 32, VD / 32), blk, 0, stream>>>(Wo, wT, VD, DIM);
  gemm_bt_bf16<<<dim3(DIM / 128, T_LEN / 128), blk, 0, stream>>>(go_bf, wT, out, T_LEN, DIM, VD, 0);
}